// Round 17
// baseline (27.716 us; speedup 1.0000x reference)
//
#include <hip/hip_runtime.h>

// Problem constants (fixed by reference): B=8, H=32, S=64, C=4096, D=128
#define BB 8
#define HH 32
#define SS 64
#define CC 4096
#define DD 128
#define NROWS (BB * HH * SS + BB * SS)   // 16896 output rows

typedef __attribute__((ext_vector_type(8))) short bf16x8;
typedef __attribute__((ext_vector_type(4))) float f32x4;

__device__ inline unsigned short f32_to_bf16_rtn(float f) {
    unsigned u = __float_as_uint(f);
    u += 0x7FFFu + ((u >> 16) & 1u);
    return (unsigned short)(u >> 16);
}
__device__ inline float bf16lo(unsigned u) { return __uint_as_float(u << 16); }
__device__ inline float bf16hi(unsigned u) { return __uint_as_float(u & 0xFFFF0000u); }

// ---------------------------------------------------------------------------
// Algebra: relu((A'@E)@W^T + b) == relu(A'@(E@W^T) + b).
// R17 = R16 with the OOB fix: E-half blocks cover exactly NROWS rows
// (528 blocks x 32 rows = 16896; R16 launched 544 -> OOB cur[] gather -> crash)
// plus a defensive wave-uniform row guard.
//
// ws layout (words), all write-before-read (0xAA-poison safe):
//   rowptr 32832 | adj 16384 | s 32768 | te 16384 | EWb (bf16) 2097152
// ---------------------------------------------------------------------------

// K1 heterogeneous blocks: 0..7 per-batch graph build (dedupe->CSR + s);
// 8..23 te table (for K2); 24..535 MFMA EW tiles; 536..1063 E-half output.
__global__ __launch_bounds__(1024) void mega(const int* __restrict__ hist,
                                             const int* __restrict__ cur,
                                             const float* __restrict__ E,
                                             const float* __restrict__ W,
                                             unsigned* __restrict__ rowptr,
                                             unsigned* __restrict__ adj,
                                             float* __restrict__ s,
                                             float* __restrict__ te,
                                             unsigned short* __restrict__ EWb,
                                             float* __restrict__ out) {
    extern __shared__ unsigned smem_u[];
    const int tid = threadIdx.x;

    if (blockIdx.x >= BB + 16 + 512) {             // ---- E-half output ----
        const int row = (blockIdx.x - (BB + 16 + 512)) * 32 + (tid >> 5);
        if (row >= NROWS) return;                  // wave-uniform guard
        const int lane32 = tid & 31;
        int b, spos, cand;
        if (row < BB * HH * SS) {
            spos = row & 63;
            b = row >> 11;
            cand = hist[row];
        } else {
            int rc = row - BB * HH * SS;
            spos = rc & 63;
            b = rc >> 6;
            cand = cur[rc];
        }
        float4 e = ((const float4*)E)[(size_t)(b * CC + cand) * 32 + lane32];
        // te cols c = 128 + 4*lane32 + q: k0 = 64+2*lane32 (q=0 sin, q=1 cos),
        // k1 = k0+1 (q=2 sin, q=3 cos); ang = spos * 10000^(-k/128)
        int k0 = 64 + lane32 * 2;
        float ang0 = (float)spos * powf(10000.0f, -(float)k0 / 128.0f);
        float ang1 = (float)spos * powf(10000.0f, -(float)(k0 + 1) / 128.0f);
        float4 o;
        o.x = e.x + sinf(ang0);
        o.y = e.y + cosf(ang0);
        o.z = e.z + sinf(ang1);
        o.w = e.w + cosf(ang1);
        ((float4*)out)[(size_t)row * 64 + 32 + lane32] = o;
        return;
    }
    if (blockIdx.x >= BB + 16) {                   // ---- EW GEMM tiles ----
        unsigned short* Abf = (unsigned short*)smem_u;         // [64][136]
        unsigned short* Wb  = Abf + 64 * 136;                  // [128][136]
        const int r0 = (blockIdx.x - BB - 16) * 64;            // global row
        for (int idx = tid; idx < 2048; idx += 1024) {         // stage E tile
            int row = idx >> 5, c4 = idx & 31;
            float4 v = ((const float4*)E)[(size_t)(r0 + row) * 32 + c4];
            ushort4 o;
            o.x = f32_to_bf16_rtn(v.x); o.y = f32_to_bf16_rtn(v.y);
            o.z = f32_to_bf16_rtn(v.z); o.w = f32_to_bf16_rtn(v.w);
            *(ushort4*)&Abf[row * 136 + c4 * 4] = o;
        }
        for (int idx = tid; idx < 4096; idx += 1024) {         // stage W [n][k]
            int n = idx >> 5, c4 = idx & 31;
            float4 v = ((const float4*)W)[idx];
            ushort4 o;
            o.x = f32_to_bf16_rtn(v.x); o.y = f32_to_bf16_rtn(v.y);
            o.z = f32_to_bf16_rtn(v.z); o.w = f32_to_bf16_rtn(v.w);
            *(ushort4*)&Wb[n * 136 + c4 * 4] = o;
        }
        __syncthreads();
        const int lane = tid & 63, wv = tid >> 6;
        const int l15 = lane & 15, l4 = lane >> 4;
        const int rb = (wv >> 2) * 16;             // wave row base (0..48)
        const int cb = (wv & 3) * 32;              // wave col base (0..96)
        f32x4 acc[2] = {{0.f, 0.f, 0.f, 0.f}, {0.f, 0.f, 0.f, 0.f}};
#pragma unroll
        for (int kt = 0; kt < 4; ++kt) {
            bf16x8 a = *(const bf16x8*)&Abf[(rb + l15) * 136 + kt * 32 + l4 * 8];
#pragma unroll
            for (int nt = 0; nt < 2; ++nt) {
                bf16x8 bb = *(const bf16x8*)&Wb[(cb + nt * 16 + l15) * 136 + kt * 32 + l4 * 8];
                acc[nt] = __builtin_amdgcn_mfma_f32_16x16x32_bf16(a, bb, acc[nt], 0, 0, 0);
            }
        }
#pragma unroll
        for (int nt = 0; nt < 2; ++nt) {
            int col = cb + nt * 16 + l15;
#pragma unroll
            for (int i = 0; i < 4; ++i) {
                int row = r0 + rb + l4 * 4 + i;
                EWb[(size_t)row * 128 + col] = f32_to_bf16_rtn(acc[nt][i]);
            }
        }
        return;
    }
    if (blockIdx.x >= BB) {                        // ---- te table (for K2) ----
        int g = (blockIdx.x - BB) * 1024 + tid;    // S*256 = 16384
        int t = g >> 8, c = g & 255, k = c >> 1;
        float ang = (float)t * powf(10000.0f, -(float)k / 128.0f);
        te[g] = (c & 1) ? cosf(ang) : sinf(ang);
        return;
    }

    // ---- graph build (one block per batch) ----
    unsigned* table = smem_u;              // 4096 hash set; ALIASED as pref later
    unsigned* cnt   = table + 4096;        // in-deg low16 | out-deg high16
    unsigned* lkeys = cnt + 4096;          // 2048 unique edge keys
    unsigned* wbase = lkeys + 2048;        // 17
    unsigned* totalp = wbase + 17;
    const int b = blockIdx.x;
    const int lane = tid & 63, wv = tid >> 6;

#pragma unroll
    for (int r = 0; r < 4; ++r) {
        int g = tid + r * 1024;
        table[g] = 0xFFFFFFFFu;
        cnt[g] = 0u;
    }
    if (tid == 0) *totalp = 0u;
    __syncthreads();

    for (int t = tid; t < HH * (SS - 1); t += 1024) {   // edge dedupe
        int h = t / 63, ss = t - h * 63;
        int base = (b * HH + h) * SS + ss;
        int i = hist[base], j = hist[base + 1];
        if (i != j) {
            unsigned key = ((unsigned)i << 12) | (unsigned)j;
            unsigned hh = (key * 2654435761u) >> 20;
            for (;;) {
                hh &= 4095u;
                unsigned old = atomicCAS(&table[hh], 0xFFFFFFFFu, key);
                if (old == 0xFFFFFFFFu) {
                    unsigned slot = atomicAdd(totalp, 1u);
                    lkeys[slot] = key;
                    atomicAdd(&cnt[key & 4095u], 1u);         // in-degree
                    atomicAdd(&cnt[key >> 12], 1u << 16);     // out-degree
                    break;
                }
                if (old == key) break;
                ++hh;
            }
        }
    }
    __syncthreads();                               // table (hash) now dead

#pragma unroll
    for (int r = 0; r < 4; ++r) {                  // s from in-degree
        int g = tid + r * 1024;
        s[b * CC + g] = sqrtf(1.0f + (float)(cnt[g] & 0xFFFFu));
    }

    // scan over out-degree -> CSR rowptr (pref aliases the dead hash table)
    unsigned* pref = table;
    {
        unsigned v0 = cnt[tid * 4]     >> 16;
        unsigned v1 = cnt[tid * 4 + 1] >> 16;
        unsigned v2 = cnt[tid * 4 + 2] >> 16;
        unsigned v3 = cnt[tid * 4 + 3] >> 16;
        unsigned tsum = v0 + v1 + v2 + v3;
        unsigned x = tsum;
#pragma unroll
        for (int off = 1; off < 64; off <<= 1) {
            unsigned y = __shfl_up(x, off);
            if (lane >= off) x += y;
        }
        if (lane == 63) wbase[wv + 1] = x;
        __syncthreads();
        if (tid == 0) {
            wbase[0] = 0u;
            for (int w = 1; w <= 16; ++w) wbase[w] += wbase[w - 1];
        }
        __syncthreads();
        unsigned texcl = wbase[wv] + x - tsum;
        pref[tid * 4]     = texcl;
        pref[tid * 4 + 1] = texcl + v0;
        pref[tid * 4 + 2] = texcl + v0 + v1;
        pref[tid * 4 + 3] = texcl + v0 + v1 + v2;
        __syncthreads();
#pragma unroll
        for (int r = 0; r < 4; ++r) {
            int g = tid + r * 1024;
            rowptr[b * 4104 + g] = pref[g];
        }
        if (tid == 0) rowptr[b * 4104 + 4096] = wbase[16];
    }
    __syncthreads();
    // outdeg (high16) dead -> high bits become scatter cursor; indeg stays low.
#pragma unroll
    for (int r = 0; r < 4; ++r) {
        int g = tid + r * 1024;
        cnt[g] &= 0xFFFFu;
    }
    __syncthreads();

    {   // adjacency scatter in CSR order; entry = j | indeg_j << 12
        unsigned total = *totalp;
        for (int e = tid; e < (int)total; e += 1024) {
            unsigned key = lkeys[e];
            unsigned i = key >> 12, j = key & 4095u;
            unsigned old = atomicAdd(&cnt[i], 1u << 16);      // cursor in high bits
            unsigned pos = pref[i] + (old >> 16);
            unsigned indegj = cnt[j] & 0xFFFFu;               // low bits stable
            adj[b * 2048 + pos] = j | (indegj << 12);
        }
    }
}

// K2: one wave per OUTPUT row, eg-half only.
// eg = relu(s_c*(s_c*EW[c] + sum_{c->j} s_j*EW[j]) + bg); out[row][0:128] += te.
__global__ __launch_bounds__(256) void apply_out(const int* __restrict__ hist,
                                                 const int* __restrict__ cur,
                                                 const float* __restrict__ s,
                                                 const unsigned* __restrict__ rowptr,
                                                 const unsigned* __restrict__ adj,
                                                 const unsigned short* __restrict__ EWb,
                                                 const float* __restrict__ bg,
                                                 const float* __restrict__ te,
                                                 float* __restrict__ out) {
    const int g = blockIdx.x * 256 + threadIdx.x;
    const int row = g >> 6, lane = g & 63;
    int b, spos, cand;
    if (row < BB * HH * SS) {
        spos = row & 63;
        b = row >> 11;
        cand = hist[row];
    } else {
        int rc = row - BB * HH * SS;
        spos = rc & 63;
        b = rc >> 6;
        cand = cur[rc];
    }
    const unsigned* ew = (const unsigned*)EWb;     // 64 u32 per row (128 bf16)
    const float si = s[b * CC + cand];
    unsigned u = ew[(size_t)(b * CC + cand) * 64 + lane];
    float ax = si * bf16lo(u), ay = si * bf16hi(u);
    unsigned p0 = rowptr[b * 4104 + cand], p1 = rowptr[b * 4104 + cand + 1];
    for (unsigned p = p0; p < p1; ++p) {
        unsigned e = adj[b * 2048 + p];
        unsigned j = e & 4095u;
        float sj = sqrtf(1.0f + (float)(e >> 12));
        unsigned uj = ew[(size_t)(b * CC + j) * 64 + lane];
        ax += sj * bf16lo(uj);
        ay += sj * bf16hi(uj);
    }
    float2 bgv = ((const float2*)bg)[lane];
    ax = fmaxf(si * ax + bgv.x, 0.f);
    ay = fmaxf(si * ay + bgv.y, 0.f);

    float2 t0 = ((const float2*)te)[spos * 128 + lane];
    ((float2*)out)[(size_t)row * 128 + lane] = make_float2(ax + t0.x, ay + t0.y);
}

extern "C" void kernel_launch(void* const* d_in, const int* in_sizes, int n_in,
                              void* d_out, int out_size, void* d_ws, size_t ws_size,
                              hipStream_t stream) {
    const int*   hist = (const int*)d_in[1];
    const int*   cur  = (const int*)d_in[2];
    const float* E    = (const float*)d_in[3];
    const float* W    = (const float*)d_in[4];
    const float* bg   = (const float*)d_in[5];
    float* out = (float*)d_out;

    unsigned* ws_u   = (unsigned*)d_ws;
    unsigned* rowptr = ws_u;                          // 32832
    unsigned* adj    = rowptr + 32832;                // 16384
    float*    sarr   = (float*)(adj + 16384);         // 32768
    float*    te     = sarr + 32768;                  // 16384
    unsigned short* EWb = (unsigned short*)(te + 16384);  // 4194304 shorts

    // 8 build + 16 te + 512 GEMM + 528 E-half (= NROWS/32 exactly) = 1064
    mega<<<BB + 16 + 512 + NROWS / 32, 1024, 52224, stream>>>(
        hist, cur, E, W, rowptr, adj, sarr, te, EWb, out);
    apply_out<<<NROWS / 4, 256, 0, stream>>>(
        hist, cur, sarr, rowptr, adj, EWb, bg, te, out);
}

// Round 18
// 25.394 us; speedup vs baseline: 1.0914x; 1.0914x over previous
//
#include <hip/hip_runtime.h>

// Problem constants (fixed by reference): B=8, H=32, S=64, C=4096, D=128
#define BB 8
#define HH 32
#define SS 64
#define CC 4096
#define DD 128

typedef __attribute__((ext_vector_type(8))) short bf16x8;
typedef __attribute__((ext_vector_type(4))) float f32x4;

__device__ inline unsigned short f32_to_bf16_rtn(float f) {
    unsigned u = __float_as_uint(f);
    u += 0x7FFFu + ((u >> 16) & 1u);
    return (unsigned short)(u >> 16);
}
__device__ inline float bf16lo(unsigned u) { return __uint_as_float(u << 16); }
__device__ inline float bf16hi(unsigned u) { return __uint_as_float(u & 0xFFFF0000u); }

// ---------------------------------------------------------------------------
// R18 = R15 verbatim (best verified: 25.5us). R16 (E-half offload) crashed
// then regressed (R17: 27.7 — dynamic-LDS occupancy cap on no-LDS blocks +
// transcendental VALU + K1 makespan growth). Reverting to best.
//
// Algebra: relu((A'@E)@W^T + b) == relu(A'@(E@W^T) + b).  EW = E@W^T is
// graph-independent -> computed in heterogeneous K1 concurrently with the
// per-batch graph build.  K2 is wave-per-OUTPUT-row; adjacency entries carry
// the dest in-degree (adj = j | indeg<<12) so s_j is VALU-recomputed.
//
// ws layout (words), all write-before-read (0xAA-poison safe):
//   rowptr 32832 | adj 16384 | s 32768 | te 16384 | EWb (bf16) 2097152
// ---------------------------------------------------------------------------

// K1: blocks 0..7 per-batch graph build (dedupe->CSR + s); blocks 8..23 te
// table; blocks 24..535 MFMA EW tiles. Dynamic LDS union: build 41KB,
// gemm 52.2KB -> smem 52224B = 3 blocks/CU.
__global__ __launch_bounds__(1024) void mega(const int* __restrict__ hist,
                                             const int* __restrict__ cur,
                                             const float* __restrict__ E,
                                             const float* __restrict__ W,
                                             unsigned* __restrict__ rowptr,
                                             unsigned* __restrict__ adj,
                                             float* __restrict__ s,
                                             float* __restrict__ te,
                                             unsigned short* __restrict__ EWb) {
    extern __shared__ unsigned smem_u[];
    const int tid = threadIdx.x;

    if (blockIdx.x >= BB + 16) {                   // ---- EW GEMM tiles ----
        unsigned short* Abf = (unsigned short*)smem_u;         // [64][136]
        unsigned short* Wb  = Abf + 64 * 136;                  // [128][136]
        const int r0 = (blockIdx.x - BB - 16) * 64;            // global row
        for (int idx = tid; idx < 2048; idx += 1024) {         // stage E tile
            int row = idx >> 5, c4 = idx & 31;
            float4 v = ((const float4*)E)[(size_t)(r0 + row) * 32 + c4];
            ushort4 o;
            o.x = f32_to_bf16_rtn(v.x); o.y = f32_to_bf16_rtn(v.y);
            o.z = f32_to_bf16_rtn(v.z); o.w = f32_to_bf16_rtn(v.w);
            *(ushort4*)&Abf[row * 136 + c4 * 4] = o;
        }
        for (int idx = tid; idx < 4096; idx += 1024) {         // stage W [n][k]
            int n = idx >> 5, c4 = idx & 31;
            float4 v = ((const float4*)W)[idx];
            ushort4 o;
            o.x = f32_to_bf16_rtn(v.x); o.y = f32_to_bf16_rtn(v.y);
            o.z = f32_to_bf16_rtn(v.z); o.w = f32_to_bf16_rtn(v.w);
            *(ushort4*)&Wb[n * 136 + c4 * 4] = o;
        }
        __syncthreads();
        const int lane = tid & 63, wv = tid >> 6;
        const int l15 = lane & 15, l4 = lane >> 4;
        const int rb = (wv >> 2) * 16;             // wave row base (0..48)
        const int cb = (wv & 3) * 32;              // wave col base (0..96)
        f32x4 acc[2] = {{0.f, 0.f, 0.f, 0.f}, {0.f, 0.f, 0.f, 0.f}};
#pragma unroll
        for (int kt = 0; kt < 4; ++kt) {
            bf16x8 a = *(const bf16x8*)&Abf[(rb + l15) * 136 + kt * 32 + l4 * 8];
#pragma unroll
            for (int nt = 0; nt < 2; ++nt) {
                bf16x8 bb = *(const bf16x8*)&Wb[(cb + nt * 16 + l15) * 136 + kt * 32 + l4 * 8];
                acc[nt] = __builtin_amdgcn_mfma_f32_16x16x32_bf16(a, bb, acc[nt], 0, 0, 0);
            }
        }
#pragma unroll
        for (int nt = 0; nt < 2; ++nt) {
            int col = cb + nt * 16 + l15;
#pragma unroll
            for (int i = 0; i < 4; ++i) {
                int row = r0 + rb + l4 * 4 + i;
                EWb[(size_t)row * 128 + col] = f32_to_bf16_rtn(acc[nt][i]);
            }
        }
        return;
    }
    if (blockIdx.x >= BB) {                        // ---- te table ----
        int g = (blockIdx.x - BB) * 1024 + tid;    // S*256 = 16384
        int t = g >> 8, c = g & 255, k = c >> 1;
        float ang = (float)t * powf(10000.0f, -(float)k / 128.0f);
        te[g] = (c & 1) ? cosf(ang) : sinf(ang);
        return;
    }

    // ---- graph build (one block per batch) ----
    unsigned* table = smem_u;              // 4096 hash set; ALIASED as pref later
    unsigned* cnt   = table + 4096;        // in-deg low16 | out-deg high16
    unsigned* lkeys = cnt + 4096;          // 2048 unique edge keys
    unsigned* wbase = lkeys + 2048;        // 17
    unsigned* totalp = wbase + 17;
    const int b = blockIdx.x;
    const int lane = tid & 63, wv = tid >> 6;

#pragma unroll
    for (int r = 0; r < 4; ++r) {
        int g = tid + r * 1024;
        table[g] = 0xFFFFFFFFu;
        cnt[g] = 0u;
    }
    if (tid == 0) *totalp = 0u;
    __syncthreads();

    for (int t = tid; t < HH * (SS - 1); t += 1024) {   // edge dedupe
        int h = t / 63, ss = t - h * 63;
        int base = (b * HH + h) * SS + ss;
        int i = hist[base], j = hist[base + 1];
        if (i != j) {
            unsigned key = ((unsigned)i << 12) | (unsigned)j;
            unsigned hh = (key * 2654435761u) >> 20;
            for (;;) {
                hh &= 4095u;
                unsigned old = atomicCAS(&table[hh], 0xFFFFFFFFu, key);
                if (old == 0xFFFFFFFFu) {
                    unsigned slot = atomicAdd(totalp, 1u);
                    lkeys[slot] = key;
                    atomicAdd(&cnt[key & 4095u], 1u);         // in-degree
                    atomicAdd(&cnt[key >> 12], 1u << 16);     // out-degree
                    break;
                }
                if (old == key) break;
                ++hh;
            }
        }
    }
    __syncthreads();                               // table (hash) now dead

#pragma unroll
    for (int r = 0; r < 4; ++r) {                  // s from in-degree
        int g = tid + r * 1024;
        s[b * CC + g] = sqrtf(1.0f + (float)(cnt[g] & 0xFFFFu));
    }

    // scan over out-degree -> CSR rowptr (pref aliases the dead hash table)
    unsigned* pref = table;
    {
        unsigned v0 = cnt[tid * 4]     >> 16;
        unsigned v1 = cnt[tid * 4 + 1] >> 16;
        unsigned v2 = cnt[tid * 4 + 2] >> 16;
        unsigned v3 = cnt[tid * 4 + 3] >> 16;
        unsigned tsum = v0 + v1 + v2 + v3;
        unsigned x = tsum;
#pragma unroll
        for (int off = 1; off < 64; off <<= 1) {
            unsigned y = __shfl_up(x, off);
            if (lane >= off) x += y;
        }
        if (lane == 63) wbase[wv + 1] = x;
        __syncthreads();
        if (tid == 0) {
            wbase[0] = 0u;
            for (int w = 1; w <= 16; ++w) wbase[w] += wbase[w - 1];
        }
        __syncthreads();
        unsigned texcl = wbase[wv] + x - tsum;
        pref[tid * 4]     = texcl;
        pref[tid * 4 + 1] = texcl + v0;
        pref[tid * 4 + 2] = texcl + v0 + v1;
        pref[tid * 4 + 3] = texcl + v0 + v1 + v2;
        __syncthreads();
#pragma unroll
        for (int r = 0; r < 4; ++r) {
            int g = tid + r * 1024;
            rowptr[b * 4104 + g] = pref[g];
        }
        if (tid == 0) rowptr[b * 4104 + 4096] = wbase[16];
    }
    __syncthreads();
    // outdeg (high16 of cnt) is now dead (encoded in rowptr) -> reuse the
    // high bits as the scatter cursor; KEEP indeg in the low bits so the
    // scatter can pack it into the adjacency entry.
#pragma unroll
    for (int r = 0; r < 4; ++r) {
        int g = tid + r * 1024;
        cnt[g] &= 0xFFFFu;
    }
    __syncthreads();

    {   // adjacency scatter in CSR order; entry = j | indeg_j << 12
        unsigned total = *totalp;
        for (int e = tid; e < (int)total; e += 1024) {
            unsigned key = lkeys[e];
            unsigned i = key >> 12, j = key & 4095u;
            unsigned old = atomicAdd(&cnt[i], 1u << 16);      // cursor in high bits
            unsigned pos = pref[i] + (old >> 16);
            unsigned indegj = cnt[j] & 0xFFFFu;               // low bits stable
            adj[b * 2048 + pos] = j | (indegj << 12);
        }
    }
}

// K2: one wave per OUTPUT row. cand uniform per wave (scalar chain), EW/E/te
// vector reads per lane, one coalesced 1KB row write. Per-edge chain is
// adj -> EW[j] only (s_j recomputed from the packed in-degree).
__global__ __launch_bounds__(256) void apply_out(const int* __restrict__ hist,
                                                 const int* __restrict__ cur,
                                                 const float* __restrict__ E,
                                                 const float* __restrict__ s,
                                                 const unsigned* __restrict__ rowptr,
                                                 const unsigned* __restrict__ adj,
                                                 const unsigned short* __restrict__ EWb,
                                                 const float* __restrict__ bg,
                                                 const float* __restrict__ te,
                                                 float* __restrict__ out) {
    const int g = blockIdx.x * 256 + threadIdx.x;
    const int row = g >> 6, lane = g & 63;
    int b, spos, cand;
    if (row < BB * HH * SS) {
        spos = row & 63;
        b = row >> 11;
        cand = hist[row];
    } else {
        int rc = row - BB * HH * SS;
        spos = rc & 63;
        b = rc >> 6;
        cand = cur[rc];
    }
    const unsigned* ew = (const unsigned*)EWb;     // 64 u32 per row (128 bf16)
    const float si = s[b * CC + cand];
    unsigned u = ew[(size_t)(b * CC + cand) * 64 + lane];
    float ax = si * bf16lo(u), ay = si * bf16hi(u);
    unsigned p0 = rowptr[b * 4104 + cand], p1 = rowptr[b * 4104 + cand + 1];
    for (unsigned p = p0; p < p1; ++p) {
        unsigned e = adj[b * 2048 + p];
        unsigned j = e & 4095u;
        float sj = sqrtf(1.0f + (float)(e >> 12));
        unsigned uj = ew[(size_t)(b * CC + j) * 64 + lane];
        ax += sj * bf16lo(uj);
        ay += sj * bf16hi(uj);
    }
    float2 bgv = ((const float2*)bg)[lane];
    ax = fmaxf(si * ax + bgv.x, 0.f);
    ay = fmaxf(si * ay + bgv.y, 0.f);
    float2 e2 = ((const float2*)E)[(size_t)(b * CC + cand) * 64 + lane];

    const float2* te2 = (const float2*)te;
    float2 t0 = te2[spos * 128 + lane];
    float2 t1 = te2[spos * 128 + 64 + lane];
    float2* out2 = (float2*)out;
    out2[(size_t)row * 128 + lane]      = make_float2(ax + t0.x, ay + t0.y);
    out2[(size_t)row * 128 + 64 + lane] = make_float2(e2.x + t1.x, e2.y + t1.y);
}

extern "C" void kernel_launch(void* const* d_in, const int* in_sizes, int n_in,
                              void* d_out, int out_size, void* d_ws, size_t ws_size,
                              hipStream_t stream) {
    const int*   hist = (const int*)d_in[1];
    const int*   cur  = (const int*)d_in[2];
    const float* E    = (const float*)d_in[3];
    const float* W    = (const float*)d_in[4];
    const float* bg   = (const float*)d_in[5];
    float* out = (float*)d_out;

    unsigned* ws_u   = (unsigned*)d_ws;
    unsigned* rowptr = ws_u;                          // 32832
    unsigned* adj    = rowptr + 32832;                // 16384
    float*    sarr   = (float*)(adj + 16384);         // 32768
    float*    te     = sarr + 32768;                  // 16384
    unsigned short* EWb = (unsigned short*)(te + 16384);  // 4194304 shorts

    mega<<<BB + 16 + 512, 1024, 52224, stream>>>(hist, cur, E, W, rowptr, adj,
                                                 sarr, te, EWb);
    apply_out<<<(BB * HH * SS + BB * SS) / 4, 256, 0, stream>>>(
        hist, cur, E, sarr, rowptr, adj, EWb, bg, te, out);
}